// Round 1
// baseline (788.527 us; speedup 1.0000x reference)
//
#include <hip/hip_runtime.h>

namespace {
constexpr int W = 1024;
constexpr int H = 1024;
constexpr int NIMG = 32;
constexpr int SROWS = 64;            // output rows per block strip
constexpr int NSTRIP = H / SROWS;    // 16
constexpr int BLOCK = 256;           // 256 threads * float4 = 1024 cols = full width
constexpr int PAD = 8;               // zero pad (floats) each side of row buffer
constexpr int RB = PAD + W + PAD;    // 1040 floats per buffered row

constexpr float C1 = 0.0004f;        // (0.01*2)^2
constexpr float C2 = 0.0036f;        // (0.03*2)^2

// normalized gaussian, sigma=1.5, win=11
constexpr float GW[11] = {
    0.00102838f, 0.00759876f, 0.03600077f, 0.10936070f, 0.21300554f,
    0.26601172f,
    0.21300554f, 0.10936070f, 0.03600077f, 0.00759876f, 0.00102838f};
}  // namespace

__device__ __forceinline__ void fma4(float4& a, float g, const float4 u) {
  a.x = fmaf(g, u.x, a.x);
  a.y = fmaf(g, u.y, a.y);
  a.z = fmaf(g, u.z, a.z);
  a.w = fmaf(g, u.w, a.w);
}
__device__ __forceinline__ void fma4sq(float4& a, float g, const float4 u) {
  a.x = fmaf(g * u.x, u.x, a.x);
  a.y = fmaf(g * u.y, u.y, a.y);
  a.z = fmaf(g * u.z, u.z, a.z);
  a.w = fmaf(g * u.w, u.w, a.w);
}

__device__ __forceinline__ void load_uv(const float4* __restrict__ p1,
                                        const float4* __restrict__ p2, int y,
                                        int tid, float4& u, float4& v) {
  if ((unsigned)y < (unsigned)H) {
    const float4 a = p1[y * (W / 4) + tid];
    const float4 b = p2[y * (W / 4) + tid];
    u = make_float4(a.x + b.x, a.y + b.y, a.z + b.z, a.w + b.w);
    v = make_float4(a.x - b.x, a.y - b.y, a.z - b.z, a.w - b.w);
  } else {
    u = make_float4(0.f, 0.f, 0.f, 0.f);
    v = u;
  }
}

// Computes sum over strip of SSIM map values; atomicAdd into ws[0] (double).
__global__ __launch_bounds__(BLOCK) void ssim_main(
    const float* __restrict__ img1, const float* __restrict__ img2,
    double* __restrict__ ws) {
  // double-buffered row buffers for the 4 vertically-blurred quantities
  __shared__ __align__(16) float buf[2][4][RB];
  __shared__ float red[BLOCK / 64];

  const int tid = threadIdx.x;
  const int bid = blockIdx.x;
  const int img = bid >> 4;             // / NSTRIP
  const int strip = bid & (NSTRIP - 1);
  const int ys = strip * SROWS;

  const float4* p1 =
      reinterpret_cast<const float4*>(img1) + (size_t)img * (W / 4) * H;
  const float4* p2 =
      reinterpret_cast<const float4*>(img2) + (size_t)img * (W / 4) * H;

  // zero the horizontal pad regions once (covered by first __syncthreads)
  if (tid < PAD) {
#pragma unroll
    for (int par = 0; par < 2; ++par)
#pragma unroll
      for (int q = 0; q < 4; ++q) {
        buf[par][q][tid] = 0.f;
        buf[par][q][PAD + W + tid] = 0.f;
      }
  }

  // register ring: last 11 rows of u=x+y, v=x-y (float4 per thread)
  float4 ru[11], rv[11];
#pragma unroll
  for (int s = 0; s < 10; ++s) load_uv(p1, p2, ys - 5 + s, tid, ru[s], rv[s]);
  float4 pu, pv;  // prefetched next row
  load_uv(p1, p2, ys + 5, tid, pu, pv);

  float acc = 0.f;

  for (int i0 = 0; i0 < SROWS; i0 += 11) {
#pragma unroll
    for (int p = 0; p < 11; ++p) {
      const int ii = i0 + p;
      if (ii < SROWS) {
        // commit prefetched row ys+5+ii into ring slot (static index)
        const int snew = (p + 10) % 11;
        ru[snew] = pu;
        rv[snew] = pv;
        // prefetch following row (latency hidden across whole body)
        load_uv(p1, p2, ys + 6 + ii, tid, pu, pv);

        // vertical 11-tap blur of u, v, u^2, v^2 at center row r = ys+ii
        float4 bu = make_float4(0.f, 0.f, 0.f, 0.f);
        float4 bv = bu, bu2 = bu, bv2 = bu;
#pragma unroll
        for (int k = 0; k < 11; ++k) {
          const int s = (p + k) % 11;  // static per (p,k)
          const float g = GW[k];
          const float4 u = ru[s];
          const float4 v = rv[s];
          fma4(bu, g, u);
          fma4(bv, g, v);
          fma4sq(bu2, g, u);
          fma4sq(bv2, g, v);
        }

        const int par = ii & 1;
        reinterpret_cast<float4*>(&buf[par][0][PAD])[tid] = bu;
        reinterpret_cast<float4*>(&buf[par][1][PAD])[tid] = bv;
        reinterpret_cast<float4*>(&buf[par][2][PAD])[tid] = bu2;
        reinterpret_cast<float4*>(&buf[par][3][PAD])[tid] = bv2;
        __syncthreads();

        // horizontal 11-tap blur from LDS: aligned b128 reads, lane stride 16B
        float hq[4][4];
#pragma unroll
        for (int q = 0; q < 4; ++q) {
          const float4* rb4 = reinterpret_cast<const float4*>(buf[par][q]);
          float f[20];  // cols 4t-8 .. 4t+11
#pragma unroll
          for (int d = 0; d < 5; ++d) {
            const float4 t = rb4[tid + d];
            f[4 * d + 0] = t.x;
            f[4 * d + 1] = t.y;
            f[4 * d + 2] = t.z;
            f[4 * d + 3] = t.w;
          }
#pragma unroll
          for (int m = 0; m < 4; ++m) {
            float s = GW[0] * f[m + 3];
#pragma unroll
            for (int k = 1; k < 11; ++k) s = fmaf(GW[k], f[m + 3 + k], s);
            hq[q][m] = s;
          }
        }

        // ssim from the 4 blurred quantities:
        // BU=mu1+mu2, BV=mu1-mu2, BU2=blur((x+y)^2), BV2=blur((x-y)^2)
#pragma unroll
        for (int m = 0; m < 4; ++m) {
          const float BU = hq[0][m], BV = hq[1][m];
          const float BU2 = hq[2][m], BV2 = hq[3][m];
          const float P = BU * BU, Q = BV * BV;
          const float PmQ = P - Q, PpQ = P + Q;
          const float An = fmaf(0.5f, PmQ, C1);                  // 2*mu1*mu2+C1
          const float Bn = fmaf(0.5f, (BU2 - BV2) - PmQ, C2);    // 2*sigma12+C2
          const float Cd = fmaf(0.5f, PpQ, C1);                  // mu1^2+mu2^2+C1
          const float Dd = fmaf(0.5f, (BU2 + BV2) - PpQ, C2);    // s1+s2+C2
          const float num = An * Bn;
          const float den = Cd * Dd;  // >= C1*C2 > 0
          float r = __builtin_amdgcn_rcpf(den);
          r = r * fmaf(-den, r, 2.f);  // one Newton step
          acc = fmaf(num, r, acc);
        }
      }
    }
  }

  // block reduction -> global double accumulator
#pragma unroll
  for (int off = 32; off > 0; off >>= 1) acc += __shfl_down(acc, off, 64);
  if ((tid & 63) == 0) red[tid >> 6] = acc;
  __syncthreads();
  if (tid == 0) {
    float t = 0.f;
#pragma unroll
    for (int wv = 0; wv < BLOCK / 64; ++wv) t += red[wv];
    atomicAdd(ws, (double)t);
  }
}

__global__ void ssim_fin(const double* __restrict__ ws,
                         float* __restrict__ out) {
  out[0] = 1.0f - (float)(ws[0] * (1.0 / ((double)NIMG * (double)W * (double)H)));
}

extern "C" void kernel_launch(void* const* d_in, const int* in_sizes, int n_in,
                              void* d_out, int out_size, void* d_ws,
                              size_t ws_size, hipStream_t stream) {
  const float* img1 = (const float*)d_in[0];
  const float* img2 = (const float*)d_in[1];
  float* out = (float*)d_out;
  double* ws = (double*)d_ws;

  hipMemsetAsync(d_ws, 0, sizeof(double), stream);
  ssim_main<<<NIMG * NSTRIP, BLOCK, 0, stream>>>(img1, img2, ws);
  ssim_fin<<<1, 1, 0, stream>>>(ws, out);
}

// Round 2
// 329.787 us; speedup vs baseline: 2.3910x; 2.3910x over previous
//
#include <hip/hip_runtime.h>

namespace {
constexpr int W = 1024;
constexpr int H = 1024;
constexpr int NIMG = 32;
constexpr int SROWS = 64;            // output rows per block strip
constexpr int NSTRIP = H / SROWS;    // 16
constexpr int BLOCK = 256;           // 256 threads * float4 = 1024 cols = full width
constexpr int PAD = 8;               // zero pad (floats) each side of row buffer
constexpr int RB = PAD + W + PAD;    // 1040 floats per buffered row

constexpr float C1 = 0.0004f;        // (0.01*2)^2
constexpr float C2 = 0.0036f;        // (0.03*2)^2

// normalized gaussian, sigma=1.5, win=11
constexpr float GW[11] = {
    0.00102838f, 0.00759876f, 0.03600077f, 0.10936070f, 0.21300554f,
    0.26601172f,
    0.21300554f, 0.10936070f, 0.03600077f, 0.00759876f, 0.00102838f};
}  // namespace

__device__ __forceinline__ void fma4(float4& a, float g, const float4 u) {
  a.x = fmaf(g, u.x, a.x);
  a.y = fmaf(g, u.y, a.y);
  a.z = fmaf(g, u.z, a.z);
  a.w = fmaf(g, u.w, a.w);
}
__device__ __forceinline__ void fma4sq(float4& a, float g, const float4 u) {
  a.x = fmaf(g * u.x, u.x, a.x);
  a.y = fmaf(g * u.y, u.y, a.y);
  a.z = fmaf(g * u.z, u.z, a.z);
  a.w = fmaf(g * u.w, u.w, a.w);
}

// Branch-free row load: clamp index into range, scale by 0/1 mask.
__device__ __forceinline__ void load_uv(const float4* __restrict__ p1,
                                        const float4* __restrict__ p2, int y,
                                        int tid, float4& u, float4& v) {
  const int yc = min(max(y, 0), H - 1);
  const float s = ((unsigned)y < (unsigned)H) ? 1.f : 0.f;
  const float4 a = p1[yc * (W / 4) + tid];
  const float4 b = p2[yc * (W / 4) + tid];
  u = make_float4((a.x + b.x) * s, (a.y + b.y) * s, (a.z + b.z) * s,
                  (a.w + b.w) * s);
  v = make_float4((a.x - b.x) * s, (a.y - b.y) * s, (a.z - b.z) * s,
                  (a.w - b.w) * s);
}

// Sum of SSIM map values over the strip; atomicAdd into ws[0] (double).
// launch_bounds(256,3): VGPR cap 170 — peak live estimate ~145, must not spill.
__global__ __launch_bounds__(BLOCK, 3) void ssim_main(
    const float* __restrict__ img1, const float* __restrict__ img2,
    double* __restrict__ ws) {
  // parity double-buffered row buffers for the 4 vertically-blurred quantities
  __shared__ __align__(16) float buf[2][4][RB];
  __shared__ float red[BLOCK / 64];

  const int tid = threadIdx.x;
  const int bid = blockIdx.x;
  const int img = bid >> 4;             // / NSTRIP
  const int strip = bid & (NSTRIP - 1);
  const int ys = strip * SROWS;

  const float4* p1 =
      reinterpret_cast<const float4*>(img1) + (size_t)img * (W / 4) * H;
  const float4* p2 =
      reinterpret_cast<const float4*>(img2) + (size_t)img * (W / 4) * H;

  // zero the horizontal pad regions once (covered by the first __syncthreads)
  if (tid < PAD) {
#pragma unroll
    for (int par = 0; par < 2; ++par)
#pragma unroll
      for (int q = 0; q < 4; ++q) {
        buf[par][q][tid] = 0.f;
        buf[par][q][PAD + W + tid] = 0.f;
      }
  }

  // shift ring: rows r-5..r+4 in ru[0..9]; pu/pv prefetch row r+5
  float4 ru[11], rv[11];
#pragma unroll
  for (int s = 0; s < 10; ++s) load_uv(p1, p2, ys - 5 + s, tid, ru[s], rv[s]);
  float4 pu, pv;
  load_uv(p1, p2, ys + 5, tid, pu, pv);

  float acc = 0.f;

  for (int ii = 0; ii < SROWS; ++ii) {  // NOT unrolled: keep body small
    // commit prefetched row r+5, start prefetch of row r+6
    ru[10] = pu;
    rv[10] = pv;
    load_uv(p1, p2, ys + ii + 6, tid, pu, pv);

    // vertical 11-tap blur of u, v, u^2, v^2 at center row r = ys+ii
    float4 bu = make_float4(0.f, 0.f, 0.f, 0.f);
    float4 bv = bu, bu2 = bu, bv2 = bu;
#pragma unroll
    for (int k = 0; k < 11; ++k) {
      const float g = GW[k];
      const float4 u = ru[k];
      const float4 v = rv[k];
      fma4(bu, g, u);
      fma4sq(bu2, g, u);
      fma4(bv, g, v);
      fma4sq(bv2, g, v);
    }

    const int par = ii & 1;
    reinterpret_cast<float4*>(&buf[par][0][PAD])[tid] = bu;
    reinterpret_cast<float4*>(&buf[par][1][PAD])[tid] = bv;
    reinterpret_cast<float4*>(&buf[par][2][PAD])[tid] = bu2;
    reinterpret_cast<float4*>(&buf[par][3][PAD])[tid] = bv2;
    __syncthreads();

    // horizontal 11-tap blur from LDS: aligned b128 reads, lane stride 16B
    float hq[4][4];
#pragma unroll
    for (int q = 0; q < 4; ++q) {
      const float4* rb4 = reinterpret_cast<const float4*>(buf[par][q]);
      float f[20];  // padded floats 4t .. 4t+19  (cols 4t-8 .. 4t+11)
#pragma unroll
      for (int d = 0; d < 5; ++d) {
        const float4 t4 = rb4[tid + d];
        f[4 * d + 0] = t4.x;
        f[4 * d + 1] = t4.y;
        f[4 * d + 2] = t4.z;
        f[4 * d + 3] = t4.w;
      }
#pragma unroll
      for (int m = 0; m < 4; ++m) {
        float s = GW[0] * f[m + 3];
#pragma unroll
        for (int k = 1; k < 11; ++k) s = fmaf(GW[k], f[m + 3 + k], s);
        hq[q][m] = s;
      }
    }

    // ssim from the 4 blurred quantities:
    // BU=mu1+mu2, BV=mu1-mu2, BU2=blur((x+y)^2), BV2=blur((x-y)^2)
#pragma unroll
    for (int m = 0; m < 4; ++m) {
      const float BU = hq[0][m], BV = hq[1][m];
      const float BU2 = hq[2][m], BV2 = hq[3][m];
      const float P = BU * BU, Q = BV * BV;
      const float PmQ = P - Q, PpQ = P + Q;
      const float An = fmaf(0.5f, PmQ, C1);                // 2*mu1*mu2+C1
      const float Bn = fmaf(0.5f, (BU2 - BV2) - PmQ, C2);  // 2*sigma12+C2
      const float Cd = fmaf(0.5f, PpQ, C1);                // mu1^2+mu2^2+C1
      const float Dd = fmaf(0.5f, (BU2 + BV2) - PpQ, C2);  // s1+s2+C2
      const float num = An * Bn;
      const float den = Cd * Dd;  // >= C1*C2 > 0
      float r = __builtin_amdgcn_rcpf(den);
      r = r * fmaf(-den, r, 2.f);  // one Newton step
      acc = fmaf(num, r, acc);
    }

    // shift the ring (80 v_mov/row — cheap, keeps indices static)
#pragma unroll
    for (int k = 0; k < 10; ++k) {
      ru[k] = ru[k + 1];
      rv[k] = rv[k + 1];
    }
  }

  // block reduction -> global double accumulator
#pragma unroll
  for (int off = 32; off > 0; off >>= 1) acc += __shfl_down(acc, off, 64);
  if ((tid & 63) == 0) red[tid >> 6] = acc;
  __syncthreads();
  if (tid == 0) {
    float t = 0.f;
#pragma unroll
    for (int wv = 0; wv < BLOCK / 64; ++wv) t += red[wv];
    atomicAdd(ws, (double)t);
  }
}

__global__ void ssim_fin(const double* __restrict__ ws,
                         float* __restrict__ out) {
  out[0] =
      1.0f - (float)(ws[0] * (1.0 / ((double)NIMG * (double)W * (double)H)));
}

extern "C" void kernel_launch(void* const* d_in, const int* in_sizes, int n_in,
                              void* d_out, int out_size, void* d_ws,
                              size_t ws_size, hipStream_t stream) {
  const float* img1 = (const float*)d_in[0];
  const float* img2 = (const float*)d_in[1];
  float* out = (float*)d_out;
  double* ws = (double*)d_ws;

  hipMemsetAsync(d_ws, 0, sizeof(double), stream);
  ssim_main<<<NIMG * NSTRIP, BLOCK, 0, stream>>>(img1, img2, ws);
  ssim_fin<<<1, 1, 0, stream>>>(ws, out);
}